// Round 1
// baseline (271.000 us; speedup 1.0000x reference)
//
#include <hip/hip_runtime.h>
#include <math.h>

#define NG 256
#define NG3 (NG*NG*NG)

constexpr float SPACING_F = 0.390625f;   // 100/256, exact
constexpr int KH = 8;                    // ceil((1.9+1.1)/spacing)
constexpr int KDIM = 17;
constexpr int KOFF = KDIM * KDIM * KDIM; // 4913

// ---------------- Stage 1: atom splat -> protein / occ byte masks ----------
__global__ void __launch_bounds__(256) splat_kernel(
    const float* __restrict__ xyz, const float* __restrict__ vdw,
    unsigned char* __restrict__ protein, unsigned char* __restrict__ occ)
{
    const int atom = blockIdx.x;
    const float ax = xyz[atom * 3 + 0];
    const float ay = xyz[atom * 3 + 1];
    const float az = xyz[atom * 3 + 2];
    const float vr = vdw[atom];
    const float br = __fadd_rn(vr, 1.1f);          // vr + SOLVENT_R, f32 like ref
    // base = floor(xyz / SPACING) in f32 IEEE, matching jnp
    const int bx = (int)floorf(__fdiv_rn(ax, SPACING_F));
    const int by = (int)floorf(__fdiv_rn(ay, SPACING_F));
    const int bz = (int)floorf(__fdiv_rn(az, SPACING_F));

    for (int o = threadIdx.x; o < KOFF; o += 256) {
        int dz = o % KDIM;
        int t  = o / KDIM;
        int dy = t % KDIM;
        int dx = t / KDIM;
        int cx = bx + dx - KH;
        int cy = by + dy - KH;
        int cz = bz + dz - KH;
        // centers = coords * SPACING (exact); diff, square, sum, sqrt — no fp-contract
        float ex = __fsub_rn(__fmul_rn((float)cx, SPACING_F), ax);
        float ey = __fsub_rn(__fmul_rn((float)cy, SPACING_F), ay);
        float ez = __fsub_rn(__fmul_rn((float)cz, SPACING_F), az);
        float s  = __fadd_rn(__fadd_rn(__fmul_rn(ex, ex), __fmul_rn(ey, ey)),
                             __fmul_rn(ez, ez));
        float d  = __fsqrt_rn(s);
        if (d < br) {
            int idx = ((((cx & 255) << 8) | (cy & 255)) << 8) | (cz & 255);
            occ[idx] = 1;                 // protein | bound_raw
            if (d < vr) protein[idx] = 1; // protein
        }
    }
}

// ------------- Stage 2: erosion algebra -> solvent byte mask ---------------
// pwb = p ? 1 : (occ && ALL 57 sphere-neighbors occ);  solvent = !pwb
__global__ void __launch_bounds__(256) solvent_kernel(
    const unsigned char* __restrict__ protein, const unsigned char* __restrict__ occ,
    unsigned char* __restrict__ solvent)
{
    int tid = blockIdx.x * 256 + threadIdx.x;
    unsigned char p = protein[tid];
    unsigned char o = occ[tid];
    unsigned char sol;
    if (!o) {
        sol = 1;
    } else if (p) {
        sol = 0;
    } else {
        int x = tid >> 16, y = (tid >> 8) & 255, z = tid & 255;
        unsigned int acc = 1;
        #pragma unroll
        for (int dx = -2; dx <= 2; ++dx)
        #pragma unroll
        for (int dy = -2; dy <= 2; ++dy)
        #pragma unroll
        for (int dz = -2; dz <= 2; ++dz) {
            if (dx * dx + dy * dy + dz * dz > 5) continue;   // constant-folded: 57 taps
            int j = ((((x + dx) & 255) << 8) | ((y + dy) & 255)) << 8 | ((z + dz) & 255);
            acc &= occ[j];
        }
        sol = acc ? 0 : 1;
    }
    solvent[tid] = sol;
}

// ------------- Stage 3: 3x3x3 separable-weight Gaussian, wrap --------------
__global__ void __launch_bounds__(256) gauss_kernel(
    const unsigned char* __restrict__ solvent, float* __restrict__ out,
    float wa, float wb)
{
    int tid = blockIdx.x * 256 + threadIdx.x;
    int x = tid >> 16, y = (tid >> 8) & 255, z = tid & 255;
    float w[3] = {wa, wb, wa};
    float acc = 0.0f;
    #pragma unroll
    for (int dx = -1; dx <= 1; ++dx) {
        int xw = ((x + dx) & 255) << 16;
        #pragma unroll
        for (int dy = -1; dy <= 1; ++dy) {
            int yw = ((y + dy) & 255) << 8;
            float wxy = w[dx + 1] * w[dy + 1];
            #pragma unroll
            for (int dz = -1; dz <= 1; ++dz) {
                int j = xw | yw | ((z + dz) & 255);
                acc += wxy * w[dz + 1] * (float)solvent[j];
            }
        }
    }
    out[tid] = acc;
}

extern "C" void kernel_launch(void* const* d_in, const int* in_sizes, int n_in,
                              void* d_out, int out_size, void* d_ws, size_t ws_size,
                              hipStream_t stream)
{
    const float* xyz = (const float*)d_in[0];
    const float* vdw = (const float*)d_in[1];
    float* out = (float*)d_out;

    unsigned char* protein = (unsigned char*)d_ws;     // 16.78 MB
    unsigned char* occ     = protein + NG3;            // 16.78 MB
    unsigned char* solvent = occ + NG3;                // 16.78 MB
    const int natoms = in_sizes[1];

    // masks must start at zero every launch (ws is re-poisoned to 0xAA)
    hipMemsetAsync(protein, 0, 2 * (size_t)NG3, stream);

    splat_kernel<<<natoms, 256, 0, stream>>>(xyz, vdw, protein, occ);
    solvent_kernel<<<NG3 / 256, 256, 0, stream>>>(protein, occ, solvent);

    // Gaussian weights, computed like the reference (float64 then cast)
    double spacing = 100.0 / 256.0;
    double sigma = 1.1 / spacing / 4.0;           // 0.704
    double a = exp(-1.0 / (2.0 * sigma * sigma)); // x=±1 tap
    double ssum = 2.0 * a + 1.0;
    double an = a / ssum, bn = 1.0 / ssum;
    double tot = 2.0 * an + bn;                   // k3 renormalization, separable
    float wa = (float)(an / tot);
    float wb = (float)(bn / tot);

    gauss_kernel<<<NG3 / 256, 256, 0, stream>>>(solvent, out, wa, wb);
}

// Round 2
// 178.184 us; speedup vs baseline: 1.5209x; 1.5209x over previous
//
#include <hip/hip_runtime.h>
#include <math.h>

#define NG 256
#define NG3 (NG*NG*NG)
#define NW (NG3/64)          // 262144 u64 words, z-packed

typedef unsigned long long u64;
typedef unsigned int u32;

constexpr float SPACING_F = 0.390625f;   // 100/256, exact
constexpr int KH = 8;                    // ceil((1.9+1.1)/spacing)
constexpr int KDIM = 17;
constexpr int KOFF = KDIM * KDIM * KDIM; // 4913

// ---------------- Stage 1: atom splat -> protein / occ byte masks ----------
__global__ void __launch_bounds__(256) splat_kernel(
    const float* __restrict__ xyz, const float* __restrict__ vdw,
    unsigned char* __restrict__ protein, unsigned char* __restrict__ occ)
{
    const int atom = blockIdx.x;
    const float ax = xyz[atom * 3 + 0];
    const float ay = xyz[atom * 3 + 1];
    const float az = xyz[atom * 3 + 2];
    const float vr = vdw[atom];
    const float br = __fadd_rn(vr, 1.1f);          // vr + SOLVENT_R, f32 like ref
    const int bx = (int)floorf(__fdiv_rn(ax, SPACING_F));
    const int by = (int)floorf(__fdiv_rn(ay, SPACING_F));
    const int bz = (int)floorf(__fdiv_rn(az, SPACING_F));

    for (int o = threadIdx.x; o < KOFF; o += 256) {
        int dz = o % KDIM;
        int t  = o / KDIM;
        int dy = t % KDIM;
        int dx = t / KDIM;
        int cx = bx + dx - KH;
        int cy = by + dy - KH;
        int cz = bz + dz - KH;
        float ex = __fsub_rn(__fmul_rn((float)cx, SPACING_F), ax);
        float ey = __fsub_rn(__fmul_rn((float)cy, SPACING_F), ay);
        float ez = __fsub_rn(__fmul_rn((float)cz, SPACING_F), az);
        float s  = __fadd_rn(__fadd_rn(__fmul_rn(ex, ex), __fmul_rn(ey, ey)),
                             __fmul_rn(ez, ez));
        float d  = __fsqrt_rn(s);
        if (d < br) {
            int idx = ((((cx & 255) << 8) | (cy & 255)) << 8) | (cz & 255);
            occ[idx] = 1;
            if (d < vr) protein[idx] = 1;
        }
    }
}

// ---------------- Stage 2a: pack byte masks into z-major bitmasks ----------
__device__ __forceinline__ u64 pack8(u64 v) {
    // bytes with 0/1 in LSB -> 8-bit mask (byte i -> bit i)
    return ((v & 0x0101010101010101ULL) * 0x0102040810204080ULL) >> 56;
}

__global__ void __launch_bounds__(256) pack_kernel(
    const u64* __restrict__ occB, const u64* __restrict__ protB,
    u64* __restrict__ occ_bits, u64* __restrict__ p_bits)
{
    int w = blockIdx.x * 256 + threadIdx.x;   // word index: covers bytes [w*64, w*64+64)
    u64 ob = 0, pb = 0;
    #pragma unroll
    for (int j = 0; j < 8; ++j) {
        ob |= pack8(occB[w * 8 + j])  << (8 * j);
        pb |= pack8(protB[w * 8 + j]) << (8 * j);
    }
    occ_bits[w] = ob;
    p_bits[w] = pb;
}

// ---------------- Stage 2b: bit-parallel erosion -> solvent bits -----------
// word layout: word = ((x<<8|y)<<2)|wz ; bit i = voxel z = wz*64+i
#define CB(x, y) (((((x) & 255) << 8) | ((y) & 255)) << 2)

__device__ __forceinline__ u64 rng5(const u64* __restrict__ B, int cb, int wz) {
    u64 C = B[cb | wz], P = B[cb | ((wz + 3) & 3)], Nw = B[cb | ((wz + 1) & 3)];
    u64 d1 = (C << 1) | (P >> 63), d2 = (C << 2) | (P >> 62);
    u64 u1 = (C >> 1) | (Nw << 63), u2 = (C >> 2) | (Nw << 62);
    return C & d1 & d2 & u1 & u2;
}
__device__ __forceinline__ u64 rng3(const u64* __restrict__ B, int cb, int wz) {
    u64 C = B[cb | wz], P = B[cb | ((wz + 3) & 3)], Nw = B[cb | ((wz + 1) & 3)];
    u64 d1 = (C << 1) | (P >> 63);
    u64 u1 = (C >> 1) | (Nw << 63);
    return C & d1 & u1;
}

__global__ void __launch_bounds__(256) solvent_bits_kernel(
    const u64* __restrict__ occ_bits, const u64* __restrict__ p_bits,
    u64* __restrict__ sol_bits)
{
    int w = blockIdx.x * 256 + threadIdx.x;
    int wz = w & 3, col = w >> 2;
    int y = col & 255, x = col >> 8;

    u64 ero = rng5(occ_bits, CB(x, y), wz);               // r2=0
    ero &= rng5(occ_bits, CB(x + 1, y), wz);              // r2=1
    ero &= rng5(occ_bits, CB(x - 1, y), wz);
    ero &= rng5(occ_bits, CB(x, y + 1), wz);
    ero &= rng5(occ_bits, CB(x, y - 1), wz);
    ero &= rng3(occ_bits, CB(x + 1, y + 1), wz);          // r2=2
    ero &= rng3(occ_bits, CB(x + 1, y - 1), wz);
    ero &= rng3(occ_bits, CB(x - 1, y + 1), wz);
    ero &= rng3(occ_bits, CB(x - 1, y - 1), wz);
    ero &= rng3(occ_bits, CB(x + 2, y), wz);              // r2=4
    ero &= rng3(occ_bits, CB(x - 2, y), wz);
    ero &= rng3(occ_bits, CB(x, y + 2), wz);
    ero &= rng3(occ_bits, CB(x, y - 2), wz);
    ero &= occ_bits[CB(x + 1, y + 2) | wz];               // r2=5: dz=0 only
    ero &= occ_bits[CB(x + 1, y - 2) | wz];
    ero &= occ_bits[CB(x - 1, y + 2) | wz];
    ero &= occ_bits[CB(x - 1, y - 2) | wz];
    ero &= occ_bits[CB(x + 2, y + 1) | wz];
    ero &= occ_bits[CB(x + 2, y - 1) | wz];
    ero &= occ_bits[CB(x - 2, y + 1) | wz];
    ero &= occ_bits[CB(x - 2, y - 1) | wz];

    u64 occw = occ_bits[w];
    u64 pw = p_bits[w];
    sol_bits[w] = ~(pw | (occw & ero));   // solvent = ~pwb
}

// ---------------- Stage 3: 3x3x3 Gaussian from bits ------------------------
// out = W0*c0 + W1*c1 + W2*c2 + W3*c3, ck = #set bits with k nonzero axes
struct Tri { u64 m1, m0, p1; };
__device__ __forceinline__ Tri tri(const u64* __restrict__ B, int x, int y, int wz) {
    int cb = CB(x, y);
    u64 C = B[cb | wz], P = B[cb | ((wz + 3) & 3)], Nw = B[cb | ((wz + 1) & 3)];
    Tri t;
    t.m0 = C;
    t.m1 = (C << 1) | (P >> 63);   // b(z-1)
    t.p1 = (C >> 1) | (Nw << 63);  // b(z+1)
    return t;
}

__global__ void __launch_bounds__(256) gauss_bits_kernel(
    const u64* __restrict__ S, float* __restrict__ out,
    float W0, float W1, float W2, float W3)
{
    int w = blockIdx.x * 256 + threadIdx.x;
    int wz = w & 3, col = w >> 2;
    int y = col & 255, x = col >> 8;

    Tri cc = tri(S, x, y, wz);
    Tri e0 = tri(S, x + 1, y, wz), e1 = tri(S, x - 1, y, wz);
    Tri e2 = tri(S, x, y + 1, wz), e3 = tri(S, x, y - 1, wz);
    Tri d0 = tri(S, x + 1, y + 1, wz), d1 = tri(S, x + 1, y - 1, wz);
    Tri d2 = tri(S, x - 1, y + 1, wz), d3 = tri(S, x - 1, y - 1, wz);

    float* outp = out + (size_t)w * 64;

    #pragma unroll
    for (int h = 0; h < 2; ++h) {
        const int sh = h * 32;
        u32 g0 = (u32)(cc.m0 >> sh);
        u32 a1[6]  = { (u32)(cc.m1 >> sh), (u32)(cc.p1 >> sh),
                       (u32)(e0.m0 >> sh), (u32)(e1.m0 >> sh),
                       (u32)(e2.m0 >> sh), (u32)(e3.m0 >> sh) };
        u32 a2[12] = { (u32)(e0.m1 >> sh), (u32)(e0.p1 >> sh),
                       (u32)(e1.m1 >> sh), (u32)(e1.p1 >> sh),
                       (u32)(e2.m1 >> sh), (u32)(e2.p1 >> sh),
                       (u32)(e3.m1 >> sh), (u32)(e3.p1 >> sh),
                       (u32)(d0.m0 >> sh), (u32)(d1.m0 >> sh),
                       (u32)(d2.m0 >> sh), (u32)(d3.m0 >> sh) };
        u32 a3[8]  = { (u32)(d0.m1 >> sh), (u32)(d0.p1 >> sh),
                       (u32)(d1.m1 >> sh), (u32)(d1.p1 >> sh),
                       (u32)(d2.m1 >> sh), (u32)(d2.p1 >> sh),
                       (u32)(d3.m1 >> sh), (u32)(d3.p1 >> sh) };
        #pragma unroll
        for (int zq = 0; zq < 8; ++zq) {          // 8 groups of 4 z -> float4 stores
            float fb[4];
            #pragma unroll
            for (int q = 0; q < 4; ++q) {
                const int z = zq * 4 + q;
                int c1 = 0, c2 = 0, c3 = 0;
                #pragma unroll
                for (int i = 0; i < 6; ++i)  c1 += (a1[i] >> z) & 1;
                #pragma unroll
                for (int i = 0; i < 12; ++i) c2 += (a2[i] >> z) & 1;
                #pragma unroll
                for (int i = 0; i < 8; ++i)  c3 += (a3[i] >> z) & 1;
                float acc = ((g0 >> z) & 1) ? W0 : 0.0f;
                acc = fmaf(W1, (float)c1, acc);
                acc = fmaf(W2, (float)c2, acc);
                acc = fmaf(W3, (float)c3, acc);
                fb[q] = acc;
            }
            float4 v = make_float4(fb[0], fb[1], fb[2], fb[3]);
            *(float4*)(outp + sh + zq * 4) = v;
        }
    }
}

extern "C" void kernel_launch(void* const* d_in, const int* in_sizes, int n_in,
                              void* d_out, int out_size, void* d_ws, size_t ws_size,
                              hipStream_t stream)
{
    const float* xyz = (const float*)d_in[0];
    const float* vdw = (const float*)d_in[1];
    float* out = (float*)d_out;

    unsigned char* protein = (unsigned char*)d_ws;     // 16.78 MB
    unsigned char* occ     = protein + NG3;            // 16.78 MB
    u64* occ_bits = (u64*)(occ + NG3);                 // 2 MB
    u64* p_bits   = occ_bits + NW;                     // 2 MB
    u64* sol_bits = p_bits + NW;                       // 2 MB
    const int natoms = in_sizes[1];

    hipMemsetAsync(protein, 0, 2 * (size_t)NG3, stream);

    splat_kernel<<<natoms, 256, 0, stream>>>(xyz, vdw, protein, occ);
    pack_kernel<<<NW / 256, 256, 0, stream>>>(
        (const u64*)occ, (const u64*)protein, occ_bits, p_bits);
    solvent_bits_kernel<<<NW / 256, 256, 0, stream>>>(occ_bits, p_bits, sol_bits);

    // Gaussian weights in f64 like the reference, cast to f32
    double spacing = 100.0 / 256.0;
    double sigma = 1.1 / spacing / 4.0;
    double a = exp(-1.0 / (2.0 * sigma * sigma));
    double ssum = 2.0 * a + 1.0;
    double an = a / ssum, bn = 1.0 / ssum;   // g1 normalized; k3 sum == 1
    float W0 = (float)(bn * bn * bn);
    float W1 = (float)(an * bn * bn);
    float W2 = (float)(an * an * bn);
    float W3 = (float)(an * an * an);

    gauss_bits_kernel<<<NW / 256, 256, 0, stream>>>(sol_bits, out, W0, W1, W2, W3);
}

// Round 3
// 141.232 us; speedup vs baseline: 1.9188x; 1.2616x over previous
//
#include <hip/hip_runtime.h>
#include <math.h>

#define NG 256
#define NG3 (NG*NG*NG)
#define NW (NG3/64)          // 262144 u64 words, z-packed

typedef unsigned long long u64;
typedef unsigned int u32;

constexpr float SPACING_F = 0.390625f;   // 100/256, exact
constexpr int KH = 8;                    // ceil((1.9+1.1)/spacing)
constexpr int KD = 17;
constexpr int NPAIR = KD * KD;           // 289 (dx,dy) pairs per atom

// word layout: word = ((x<<8|y)<<2)|wz ; bit i = voxel z = wz*64+i
#define CB(x, y) (((((x) & 255) << 8) | ((y) & 255)) << 2)

// ------------- Stage 1: splat atoms straight into z-packed bitmasks --------
// thread = (atom, dx, dy). Per-voxel f32 math is op-identical to the
// reference (fdiv/fmul/fadd/fsqrt _rn, same association) -> bit-exact masks.
__global__ void __launch_bounds__(256) splat_bits_kernel(
    const float* __restrict__ xyz, const float* __restrict__ vdw,
    u64* __restrict__ occ_bits, u64* __restrict__ p_bits, int natoms)
{
    int t = blockIdx.x * 256 + threadIdx.x;
    if (t >= natoms * NPAIR) return;
    int atom = t / NPAIR;
    int pr = t - atom * NPAIR;
    int dx = pr / KD - KH;
    int dy = pr - (pr / KD) * KD - KH;

    const float ax = xyz[atom * 3 + 0];
    const float ay = xyz[atom * 3 + 1];
    const float az = xyz[atom * 3 + 2];
    const float vr = vdw[atom];
    const float br = __fadd_rn(vr, 1.1f);
    const int bx = (int)floorf(__fdiv_rn(ax, SPACING_F));
    const int by = (int)floorf(__fdiv_rn(ay, SPACING_F));
    const int bz = (int)floorf(__fdiv_rn(az, SPACING_F));

    const int cx = bx + dx, cy = by + dy;
    float ex = __fsub_rn(__fmul_rn((float)cx, SPACING_F), ax);
    float ey = __fsub_rn(__fmul_rn((float)cy, SPACING_F), ay);
    float rxy2 = __fadd_rn(__fmul_rn(ex, ex), __fmul_rn(ey, ey));
    // Early-out: s = rxy2 + ez^2 >= rxy2 (RN of nonneg add is monotone) and
    // fsqrt_rn(fmul_rn(br,br)) == br  =>  rxy2 >= br^2 implies d >= br always.
    if (rxy2 >= __fmul_rn(br, br)) return;

    u32 mo = 0, mp = 0;
    #pragma unroll
    for (int k = 0; k < KD; ++k) {
        int cz = bz + k - KH;
        float ez = __fsub_rn(__fmul_rn((float)cz, SPACING_F), az);
        float s = __fadd_rn(rxy2, __fmul_rn(ez, ez));   // (ex2+ey2)+ez2, same assoc
        float d = __fsqrt_rn(s);
        mo |= (d < br) ? (1u << k) : 0u;
        mp |= (d < vr) ? (1u << k) : 0u;
    }
    if (!mo) return;

    const int cb = CB(cx, cy);
    const int zA = (bz - KH) & 255;       // z of mask bit 0 (wrapped)
    const int wa = zA >> 6;
    const int off = zA & 63;

    u64 lo = (u64)mo << off;
    u64 hi = off ? ((u64)mo >> (64 - off)) : 0ULL;
    if (lo) atomicOr(&occ_bits[cb | wa], lo);
    if (hi) atomicOr(&occ_bits[cb | ((wa + 1) & 3)], hi);
    if (mp) {
        u64 plo = (u64)mp << off;
        u64 phi = off ? ((u64)mp >> (64 - off)) : 0ULL;
        if (plo) atomicOr(&p_bits[cb | wa], plo);
        if (phi) atomicOr(&p_bits[cb | ((wa + 1) & 3)], phi);
    }
}

// ---------------- Stage 2: bit-parallel erosion -> solvent bits ------------
__device__ __forceinline__ u64 rng5(const u64* __restrict__ B, int cb, int wz) {
    u64 C = B[cb | wz], P = B[cb | ((wz + 3) & 3)], Nw = B[cb | ((wz + 1) & 3)];
    u64 d1 = (C << 1) | (P >> 63), d2 = (C << 2) | (P >> 62);
    u64 u1 = (C >> 1) | (Nw << 63), u2 = (C >> 2) | (Nw << 62);
    return C & d1 & d2 & u1 & u2;
}
__device__ __forceinline__ u64 rng3(const u64* __restrict__ B, int cb, int wz) {
    u64 C = B[cb | wz], P = B[cb | ((wz + 3) & 3)], Nw = B[cb | ((wz + 1) & 3)];
    u64 d1 = (C << 1) | (P >> 63);
    u64 u1 = (C >> 1) | (Nw << 63);
    return C & d1 & u1;
}

__global__ void __launch_bounds__(256) solvent_bits_kernel(
    const u64* __restrict__ occ_bits, const u64* __restrict__ p_bits,
    u64* __restrict__ sol_bits)
{
    int w = blockIdx.x * 256 + threadIdx.x;
    int wz = w & 3, col = w >> 2;
    int y = col & 255, x = col >> 8;

    u64 ero = rng5(occ_bits, CB(x, y), wz);               // r2=0
    ero &= rng5(occ_bits, CB(x + 1, y), wz);              // r2=1
    ero &= rng5(occ_bits, CB(x - 1, y), wz);
    ero &= rng5(occ_bits, CB(x, y + 1), wz);
    ero &= rng5(occ_bits, CB(x, y - 1), wz);
    ero &= rng3(occ_bits, CB(x + 1, y + 1), wz);          // r2=2
    ero &= rng3(occ_bits, CB(x + 1, y - 1), wz);
    ero &= rng3(occ_bits, CB(x - 1, y + 1), wz);
    ero &= rng3(occ_bits, CB(x - 1, y - 1), wz);
    ero &= rng3(occ_bits, CB(x + 2, y), wz);              // r2=4
    ero &= rng3(occ_bits, CB(x - 2, y), wz);
    ero &= rng3(occ_bits, CB(x, y + 2), wz);
    ero &= rng3(occ_bits, CB(x, y - 2), wz);
    ero &= occ_bits[CB(x + 1, y + 2) | wz];               // r2=5: dz=0 only
    ero &= occ_bits[CB(x + 1, y - 2) | wz];
    ero &= occ_bits[CB(x - 1, y + 2) | wz];
    ero &= occ_bits[CB(x - 1, y - 2) | wz];
    ero &= occ_bits[CB(x + 2, y + 1) | wz];
    ero &= occ_bits[CB(x + 2, y - 1) | wz];
    ero &= occ_bits[CB(x - 2, y + 1) | wz];
    ero &= occ_bits[CB(x - 2, y - 1) | wz];

    u64 occw = occ_bits[w];
    u64 pw = p_bits[w];
    sol_bits[w] = ~(pw | (occw & ero));   // solvent = ~pwb
}

// ---------------- Stage 3: 3x3x3 Gaussian from bits ------------------------
struct Tri { u64 m1, m0, p1; };
__device__ __forceinline__ Tri tri(const u64* __restrict__ B, int x, int y, int wz) {
    int cb = CB(x, y);
    u64 C = B[cb | wz], P = B[cb | ((wz + 3) & 3)], Nw = B[cb | ((wz + 1) & 3)];
    Tri t;
    t.m0 = C;
    t.m1 = (C << 1) | (P >> 63);   // b(z-1)
    t.p1 = (C >> 1) | (Nw << 63);  // b(z+1)
    return t;
}

__global__ void __launch_bounds__(256) gauss_bits_kernel(
    const u64* __restrict__ S, float* __restrict__ out,
    float W0, float W1, float W2, float W3)
{
    __shared__ float lds[256][33];           // stride 33: ~2-way banks both sides
    const int tid = threadIdx.x;
    const int w = blockIdx.x * 256 + tid;
    const int wz = w & 3, col = w >> 2;
    const int y = col & 255, x = col >> 8;

    Tri cc = tri(S, x, y, wz);
    Tri e0 = tri(S, x + 1, y, wz), e1 = tri(S, x - 1, y, wz);
    Tri e2 = tri(S, x, y + 1, wz), e3 = tri(S, x, y - 1, wz);
    Tri d0 = tri(S, x + 1, y + 1, wz), d1 = tri(S, x + 1, y - 1, wz);
    Tri d2 = tri(S, x - 1, y + 1, wz), d3 = tri(S, x - 1, y - 1, wz);

    float* blk_out = out + (size_t)blockIdx.x * 256 * 64;

    #pragma unroll
    for (int h = 0; h < 2; ++h) {
        const int sh = h * 32;
        u32 g0 = (u32)(cc.m0 >> sh);
        u32 a1[6]  = { (u32)(cc.m1 >> sh), (u32)(cc.p1 >> sh),
                       (u32)(e0.m0 >> sh), (u32)(e1.m0 >> sh),
                       (u32)(e2.m0 >> sh), (u32)(e3.m0 >> sh) };
        u32 a2[12] = { (u32)(e0.m1 >> sh), (u32)(e0.p1 >> sh),
                       (u32)(e1.m1 >> sh), (u32)(e1.p1 >> sh),
                       (u32)(e2.m1 >> sh), (u32)(e2.p1 >> sh),
                       (u32)(e3.m1 >> sh), (u32)(e3.p1 >> sh),
                       (u32)(d0.m0 >> sh), (u32)(d1.m0 >> sh),
                       (u32)(d2.m0 >> sh), (u32)(d3.m0 >> sh) };
        u32 a3[8]  = { (u32)(d0.m1 >> sh), (u32)(d0.p1 >> sh),
                       (u32)(d1.m1 >> sh), (u32)(d1.p1 >> sh),
                       (u32)(d2.m1 >> sh), (u32)(d2.p1 >> sh),
                       (u32)(d3.m1 >> sh), (u32)(d3.p1 >> sh) };
        #pragma unroll
        for (int z = 0; z < 32; ++z) {
            int c1 = 0, c2 = 0, c3 = 0;
            #pragma unroll
            for (int i = 0; i < 6; ++i)  c1 += (a1[i] >> z) & 1;
            #pragma unroll
            for (int i = 0; i < 12; ++i) c2 += (a2[i] >> z) & 1;
            #pragma unroll
            for (int i = 0; i < 8; ++i)  c3 += (a3[i] >> z) & 1;
            float acc = ((g0 >> z) & 1) ? W0 : 0.0f;
            acc = fmaf(W1, (float)c1, acc);
            acc = fmaf(W2, (float)c2, acc);
            acc = fmaf(W3, (float)c3, acc);
            lds[tid][z] = acc;
        }
        __syncthreads();
        // drain: wave-coalesced float4 stores, full 64B lines
        #pragma unroll
        for (int k = 0; k < 8; ++k) {
            int i = tid + k * 256;        // float4 index within half-region
            int wl = i >> 3;              // local word 0..255
            int zo = (i & 7) * 4;         // 0,4,...,28
            float4 v = make_float4(lds[wl][zo], lds[wl][zo + 1],
                                   lds[wl][zo + 2], lds[wl][zo + 3]);
            *(float4*)(blk_out + (size_t)wl * 64 + sh + zo) = v;
        }
        __syncthreads();
    }
}

extern "C" void kernel_launch(void* const* d_in, const int* in_sizes, int n_in,
                              void* d_out, int out_size, void* d_ws, size_t ws_size,
                              hipStream_t stream)
{
    const float* xyz = (const float*)d_in[0];
    const float* vdw = (const float*)d_in[1];
    float* out = (float*)d_out;

    u64* occ_bits = (u64*)d_ws;          // 2 MB
    u64* p_bits   = occ_bits + NW;       // 2 MB
    u64* sol_bits = p_bits + NW;         // 2 MB
    const int natoms = in_sizes[1];

    hipMemsetAsync(occ_bits, 0, 2 * NW * sizeof(u64), stream);

    int nthreads = natoms * NPAIR;
    splat_bits_kernel<<<(nthreads + 255) / 256, 256, 0, stream>>>(
        xyz, vdw, occ_bits, p_bits, natoms);
    solvent_bits_kernel<<<NW / 256, 256, 0, stream>>>(occ_bits, p_bits, sol_bits);

    // Gaussian weights in f64 like the reference, cast to f32
    double spacing = 100.0 / 256.0;
    double sigma = 1.1 / spacing / 4.0;
    double a = exp(-1.0 / (2.0 * sigma * sigma));
    double ssum = 2.0 * a + 1.0;
    double an = a / ssum, bn = 1.0 / ssum;   // normalized 1D taps; k3 sum == 1
    float W0 = (float)(bn * bn * bn);
    float W1 = (float)(an * bn * bn);
    float W2 = (float)(an * an * bn);
    float W3 = (float)(an * an * an);

    gauss_bits_kernel<<<NW / 256, 256, 0, stream>>>(sol_bits, out, W0, W1, W2, W3);
}

// Round 4
// 119.818 us; speedup vs baseline: 2.2618x; 1.1787x over previous
//
#include <hip/hip_runtime.h>
#include <math.h>

#define NG 256
#define NG3 (NG*NG*NG)
#define NW (NG3/64)          // 262144 u64 words, z-packed

typedef unsigned long long u64;
typedef unsigned int u32;

constexpr float SPACING_F = 0.390625f;   // 100/256, exact
constexpr int KH = 8;                    // ceil((1.9+1.1)/spacing)
constexpr int KD = 17;
constexpr int NPAIR = KD * KD;           // 289 (dx,dy) pairs per atom

// word layout: word = ((x<<8|y)<<2)|wz ; bit i = voxel z = wz*64+i
#define CB(x, y) (((((x) & 255) << 8) | ((y) & 255)) << 2)

// ------------- Stage 1: splat atoms straight into z-packed bitmasks --------
__global__ void __launch_bounds__(256) splat_bits_kernel(
    const float* __restrict__ xyz, const float* __restrict__ vdw,
    u64* __restrict__ occ_bits, u64* __restrict__ p_bits, int natoms)
{
    int t = blockIdx.x * 256 + threadIdx.x;
    if (t >= natoms * NPAIR) return;
    int atom = t / NPAIR;
    int pr = t - atom * NPAIR;
    int dx = pr / KD - KH;
    int dy = pr - (pr / KD) * KD - KH;

    const float ax = xyz[atom * 3 + 0];
    const float ay = xyz[atom * 3 + 1];
    const float az = xyz[atom * 3 + 2];
    const float vr = vdw[atom];
    const float br = __fadd_rn(vr, 1.1f);
    const int bx = (int)floorf(__fdiv_rn(ax, SPACING_F));
    const int by = (int)floorf(__fdiv_rn(ay, SPACING_F));
    const int bz = (int)floorf(__fdiv_rn(az, SPACING_F));

    const int cx = bx + dx, cy = by + dy;
    float ex = __fsub_rn(__fmul_rn((float)cx, SPACING_F), ax);
    float ey = __fsub_rn(__fmul_rn((float)cy, SPACING_F), ay);
    float rxy2 = __fadd_rn(__fmul_rn(ex, ex), __fmul_rn(ey, ey));
    // Early-out: RN add of nonneg is monotone and fsqrt_rn(fmul_rn(br,br))==br
    if (rxy2 >= __fmul_rn(br, br)) return;

    u32 mo = 0, mp = 0;
    #pragma unroll
    for (int k = 0; k < KD; ++k) {
        int cz = bz + k - KH;
        float ez = __fsub_rn(__fmul_rn((float)cz, SPACING_F), az);
        float s = __fadd_rn(rxy2, __fmul_rn(ez, ez));   // same assoc as ref
        float d = __fsqrt_rn(s);
        mo |= (d < br) ? (1u << k) : 0u;
        mp |= (d < vr) ? (1u << k) : 0u;
    }
    if (!mo) return;

    const int cb = CB(cx, cy);
    const int zA = (bz - KH) & 255;       // z of mask bit 0 (wrapped)
    const int wa = zA >> 6;
    const int off = zA & 63;

    u64 lo = (u64)mo << off;
    u64 hi = off ? ((u64)mo >> (64 - off)) : 0ULL;
    if (lo) atomicOr(&occ_bits[cb | wa], lo);
    if (hi) atomicOr(&occ_bits[cb | ((wa + 1) & 3)], hi);
    if (mp) {
        u64 plo = (u64)mp << off;
        u64 phi = off ? ((u64)mp >> (64 - off)) : 0ULL;
        if (plo) atomicOr(&p_bits[cb | wa], plo);
        if (phi) atomicOr(&p_bits[cb | ((wa + 1) & 3)], phi);
    }
}

// ---------------- Stage 2: bit-parallel erosion -> solvent bits ------------
__device__ __forceinline__ u64 rng5(const u64* __restrict__ B, int cb, int wz) {
    u64 C = B[cb | wz], P = B[cb | ((wz + 3) & 3)], Nw = B[cb | ((wz + 1) & 3)];
    u64 d1 = (C << 1) | (P >> 63), d2 = (C << 2) | (P >> 62);
    u64 u1 = (C >> 1) | (Nw << 63), u2 = (C >> 2) | (Nw << 62);
    return C & d1 & d2 & u1 & u2;
}
__device__ __forceinline__ u64 rng3(const u64* __restrict__ B, int cb, int wz) {
    u64 C = B[cb | wz], P = B[cb | ((wz + 3) & 3)], Nw = B[cb | ((wz + 1) & 3)];
    u64 d1 = (C << 1) | (P >> 63);
    u64 u1 = (C >> 1) | (Nw << 63);
    return C & d1 & u1;
}

__global__ void __launch_bounds__(256) solvent_bits_kernel(
    const u64* __restrict__ occ_bits, const u64* __restrict__ p_bits,
    u64* __restrict__ sol_bits)
{
    int w = blockIdx.x * 256 + threadIdx.x;
    int wz = w & 3, col = w >> 2;
    int y = col & 255, x = col >> 8;

    u64 ero = rng5(occ_bits, CB(x, y), wz);               // r2=0
    ero &= rng5(occ_bits, CB(x + 1, y), wz);              // r2=1
    ero &= rng5(occ_bits, CB(x - 1, y), wz);
    ero &= rng5(occ_bits, CB(x, y + 1), wz);
    ero &= rng5(occ_bits, CB(x, y - 1), wz);
    ero &= rng3(occ_bits, CB(x + 1, y + 1), wz);          // r2=2
    ero &= rng3(occ_bits, CB(x + 1, y - 1), wz);
    ero &= rng3(occ_bits, CB(x - 1, y + 1), wz);
    ero &= rng3(occ_bits, CB(x - 1, y - 1), wz);
    ero &= rng3(occ_bits, CB(x + 2, y), wz);              // r2=4
    ero &= rng3(occ_bits, CB(x - 2, y), wz);
    ero &= rng3(occ_bits, CB(x, y + 2), wz);
    ero &= rng3(occ_bits, CB(x, y - 2), wz);
    ero &= occ_bits[CB(x + 1, y + 2) | wz];               // r2=5: dz=0 only
    ero &= occ_bits[CB(x + 1, y - 2) | wz];
    ero &= occ_bits[CB(x - 1, y + 2) | wz];
    ero &= occ_bits[CB(x - 1, y - 2) | wz];
    ero &= occ_bits[CB(x + 2, y + 1) | wz];
    ero &= occ_bits[CB(x + 2, y - 1) | wz];
    ero &= occ_bits[CB(x - 2, y + 1) | wz];
    ero &= occ_bits[CB(x - 2, y - 1) | wz];

    u64 occw = occ_bits[w];
    u64 pw = p_bits[w];
    sol_bits[w] = ~(pw | (occw & ero));   // solvent = ~pwb
}

// ---------------- Stage 3: 3x3x3 Gaussian from bits (CSA + byte-spread) ----
struct Tri { u64 m1, m0, p1; };
__device__ __forceinline__ Tri tri(const u64* __restrict__ B, int x, int y, int wz) {
    int cb = CB(x, y);
    u64 C = B[cb | wz], P = B[cb | ((wz + 3) & 3)], Nw = B[cb | ((wz + 1) & 3)];
    Tri t;
    t.m0 = C;
    t.m1 = (C << 1) | (P >> 63);   // b(z-1)
    t.p1 = (C >> 1) | (Nw << 63);  // b(z+1)
    return t;
}

__device__ __forceinline__ void csa(u64 a, u64 b, u64 c, u64& s, u64& cy) {
    u64 t = a ^ b;
    s = t ^ c;
    cy = (a & b) | (t & c);
}

__global__ void __launch_bounds__(256) gauss_bits_kernel(
    const u64* __restrict__ S, float* __restrict__ out,
    float W0, float W1, float W2, float W3)
{
    __shared__ float lutA[256];              // W0*g + W1*c1 + W2*c2 (exact fma chain)
    __shared__ float lds[256][33];           // output staging, conflict-free stride
    const int tid = threadIdx.x;
    {
        int g = tid & 1, c1v = (tid >> 1) & 7, c2v = (tid >> 4) & 15;
        float acc = g ? W0 : 0.0f;
        acc = fmaf(W1, (float)c1v, acc);
        acc = fmaf(W2, (float)c2v, acc);
        lutA[tid] = acc;
    }
    __syncthreads();

    const int w = blockIdx.x * 256 + tid;
    const int wz = w & 3, col = w >> 2;
    const int y = col & 255, x = col >> 8;

    Tri cc = tri(S, x, y, wz);
    Tri e0 = tri(S, x + 1, y, wz), e1 = tri(S, x - 1, y, wz);
    Tri e2 = tri(S, x, y + 1, wz), e3 = tri(S, x, y - 1, wz);
    Tri d0 = tri(S, x + 1, y + 1, wz), d1 = tri(S, x + 1, y - 1, wz);
    Tri d2 = tri(S, x - 1, y + 1, wz), d3 = tri(S, x - 1, y - 1, wz);

    // ---- c1: 6 face/z-neighbors -> 3 counter planes --------------------
    u64 sa, ca, sb, cb2;
    csa(cc.m1, cc.p1, e0.m0, sa, ca);
    csa(e1.m0, e2.m0, e3.m0, sb, cb2);
    u64 c1b0 = sa ^ sb; u64 h = sa & sb;
    u64 c1b1, c1b2;
    csa(ca, cb2, h, c1b1, c1b2);

    // ---- c2: 12 edge-neighbors -> 4 counter planes ---------------------
    u64 s1, k1, s2, k2, s3, k3, s4, k4;
    csa(e0.m1, e0.p1, e1.m1, s1, k1);
    csa(e1.p1, e2.m1, e2.p1, s2, k2);
    csa(e3.m1, e3.p1, d0.m0, s3, k3);
    csa(d1.m0, d2.m0, d3.m0, s4, k4);
    u64 t5, kt;
    csa(s1, s2, s3, t5, kt);
    u64 c2b0 = t5 ^ s4; u64 h0 = t5 & s4;
    u64 u_, ku, v_, kv;
    csa(k1, k2, k3, u_, ku);
    csa(k4, kt, h0, v_, kv);
    u64 c2b1 = u_ ^ v_; u64 h1 = u_ & v_;
    u64 c2b2, c2b3;
    csa(ku, kv, h1, c2b2, c2b3);

    // ---- c3: 8 corner-neighbors -> 4 counter planes --------------------
    u64 p1s, p1c, p2s, p2c;
    csa(d0.m1, d0.p1, d1.m1, p1s, p1c);
    csa(d1.p1, d2.m1, d2.p1, p2s, p2c);
    u64 t3, kt3;
    csa(p1s, p2s, d3.m1, t3, kt3);
    u64 c3b0 = t3 ^ d3.p1; u64 h3 = t3 & d3.p1;
    u64 u3, ku3;
    csa(p1c, p2c, kt3, u3, ku3);
    u64 c3b1 = u3 ^ h3; u64 h4 = u3 & h3;
    u64 c3b2 = ku3 ^ h4, c3b3 = ku3 & h4;

    float* blk_out = out + (size_t)blockIdx.x * 256 * 64;

    #pragma unroll
    for (int hh = 0; hh < 2; ++hh) {
        const int sh = hh * 32;
        u32 pA[8] = { (u32)(cc.m0 >> sh), (u32)(c1b0 >> sh), (u32)(c1b1 >> sh),
                      (u32)(c1b2 >> sh), (u32)(c2b0 >> sh), (u32)(c2b1 >> sh),
                      (u32)(c2b2 >> sh), (u32)(c2b3 >> sh) };
        u32 pB[4] = { (u32)(c3b0 >> sh), (u32)(c3b1 >> sh),
                      (u32)(c3b2 >> sh), (u32)(c3b3 >> sh) };
        #pragma unroll
        for (int z0 = 0; z0 < 8; ++z0) {
            u32 accA = 0, accB = 0;
            #pragma unroll
            for (int j = 0; j < 8; ++j) accA |= ((pA[j] >> z0) & 0x01010101u) << j;
            #pragma unroll
            for (int j = 0; j < 4; ++j) accB |= ((pB[j] >> z0) & 0x01010101u) << j;
            #pragma unroll
            for (int b = 0; b < 4; ++b) {
                int idxA = (accA >> (8 * b)) & 255;
                int c3v  = (accB >> (8 * b)) & 15;
                float val = fmaf(W3, (float)c3v, lutA[idxA]);
                lds[tid][z0 + 8 * b] = val;
            }
        }
        __syncthreads();
        // drain: wave-coalesced float4 stores, full 64B lines
        #pragma unroll
        for (int k = 0; k < 8; ++k) {
            int i = tid + k * 256;
            int wl = i >> 3;
            int zo = (i & 7) * 4;
            float4 v = make_float4(lds[wl][zo], lds[wl][zo + 1],
                                   lds[wl][zo + 2], lds[wl][zo + 3]);
            *(float4*)(blk_out + (size_t)wl * 64 + sh + zo) = v;
        }
        __syncthreads();
    }
}

extern "C" void kernel_launch(void* const* d_in, const int* in_sizes, int n_in,
                              void* d_out, int out_size, void* d_ws, size_t ws_size,
                              hipStream_t stream)
{
    const float* xyz = (const float*)d_in[0];
    const float* vdw = (const float*)d_in[1];
    float* out = (float*)d_out;

    u64* occ_bits = (u64*)d_ws;          // 2 MB
    u64* p_bits   = occ_bits + NW;       // 2 MB
    u64* sol_bits = p_bits + NW;         // 2 MB
    const int natoms = in_sizes[1];

    hipMemsetAsync(occ_bits, 0, 2 * NW * sizeof(u64), stream);

    int nthreads = natoms * NPAIR;
    splat_bits_kernel<<<(nthreads + 255) / 256, 256, 0, stream>>>(
        xyz, vdw, occ_bits, p_bits, natoms);
    solvent_bits_kernel<<<NW / 256, 256, 0, stream>>>(occ_bits, p_bits, sol_bits);

    // Gaussian weights in f64 like the reference, cast to f32
    double spacing = 100.0 / 256.0;
    double sigma = 1.1 / spacing / 4.0;
    double a = exp(-1.0 / (2.0 * sigma * sigma));
    double ssum = 2.0 * a + 1.0;
    double an = a / ssum, bn = 1.0 / ssum;   // normalized 1D taps; k3 sum == 1
    float W0 = (float)(bn * bn * bn);
    float W1 = (float)(an * bn * bn);
    float W2 = (float)(an * an * bn);
    float W3 = (float)(an * an * an);

    gauss_bits_kernel<<<NW / 256, 256, 0, stream>>>(sol_bits, out, W0, W1, W2, W3);
}